// Round 3
// baseline (80.810 us; speedup 1.0000x reference)
//
#include <hip/hip_runtime.h>
#include <float.h>

#define N_SRC 20000
#define N_TAR 20000
#define TPB 512                    // 8 waves/block
#define SPLITS 16                  // source splits (grid.y)
#define TILES 40                   // 32-source tiles per split; 16*40*32 = 20480 >= 20000
#define TGRP 40                    // target-strip groups (grid.x)
#define NSTRIPS (TGRP * 8)         // 320 strips per set; 2 sets/wave -> 640 strips = 20480 targets
#define FBLOCKS ((N_TAR + 255) / 256)

typedef _Float16 half8 __attribute__((ext_vector_type(8)));
typedef float floatx16 __attribute__((ext_vector_type(16)));

// q(t,s) = 0.5||s||^2 - t.s, so 0.5*d2 = 0.5||t||^2 + q.
// One mfma_f32_32x32x16_f16 computes a 32x32 tile of q directly:
//   A row (target t): k0-8 = -t split-f16 cross terms, k9-10 = 1.0
//   B col (source s): k0-8 = s split-f16 terms,        k9-10 = split 0.5||s||^2
// split-f16 (hi/lo) keeps |q error| ~5e-6 (dropped lo*lo only).
// A layout: A[m=lane&31][k=(lane>>5)*8+j]; B[k=(lane>>5)*8+j][n=lane&31];
// C/D: col=lane&31, row=(reg&3)+8*(reg>>2)+4*(lane>>5)  [m74/m101].
//
// R2 change vs R1 (76.4us): the dominant per-kernel cost is LDS READ BW
// (1 ds_read_b128 per wave per tile, 8x re-read per block = ~414 MB @ 69 TB/s).
// Each wave now owns TWO target strips (a0/a1, m0/m1): one B read feeds 2 MFMAs,
// halving LDS read traffic. SPLITS back to 16 (single-phase staging) keeps the
// grid at 640 blocks; staging traffic also halves vs R1 (26 MB vs 51 MB).
__global__ __launch_bounds__(TPB) void nn_mfma(
    const float* __restrict__ src, const float* __restrict__ tar,
    float* __restrict__ part, float* __restrict__ out)
{
    if (blockIdx.x == 0 && blockIdx.y == 0 && threadIdx.x == 0) out[0] = 0.f;

    __shared__ alignas(16) _Float16 lds[TILES * 32 * 16];  // 40 KB

    const int tid  = threadIdx.x;
    const int lane = tid & 63;
    const int col  = lane & 31;
    const int half = (lane >> 5) & 1;
    const int wave = tid >> 6;

    // ---- stage B fragments for this split's 1280 sources ----
    const int sbase = blockIdx.y * (TILES * 32);
    for (int ls = tid; ls < TILES * 32; ls += TPB) {
        const int s = sbase + ls;
        half8 f0 = {0, 0, 0, 0, 0, 0, 0, 0};
        half8 f1 = {0, 0, 0, 0, 0, 0, 0, 0};
        if (s < N_SRC) {
            const float x = src[s * 3 + 0];
            const float y = src[s * 3 + 1];
            const float z = src[s * 3 + 2];
            const _Float16 xh = (_Float16)x, yh = (_Float16)y, zh = (_Float16)z;
            const _Float16 xl = (_Float16)(x - (float)xh);
            const _Float16 yl = (_Float16)(y - (float)yh);
            const _Float16 zl = (_Float16)(z - (float)zh);
            const float nrm = 0.5f * (x * x + y * y + z * z);
            const _Float16 nh = (_Float16)nrm;
            const _Float16 nl = (_Float16)(nrm - (float)nh);
            f0 = (half8){xh, yh, zh, xh, yh, zh, xl, yl};
            f1 = (half8){zl, nh, nl, 0, 0, 0, 0, 0};
        } else {
            f1 = (half8){0, (_Float16)30000.f, 0, 0, 0, 0, 0, 0}; // never the min
        }
        *(half8*)&lds[ls * 16 + 0] = f0;
        *(half8*)&lds[ls * 16 + 8] = f1;
    }

    // ---- build TWO A fragments: this wave's 2x32 targets ----
    const int strip0 = blockIdx.x * 8 + wave;
    const int strip1 = strip0 + NSTRIPS;
    half8 a0, a1;
    {
        const int t = min(strip0 * 32 + col, N_TAR - 1);
        const float tx = tar[t * 3 + 0];
        const float ty = tar[t * 3 + 1];
        const float tz = tar[t * 3 + 2];
        const _Float16 txh = (_Float16)tx, tyh = (_Float16)ty, tzh = (_Float16)tz;
        const _Float16 txl = (_Float16)(tx - (float)txh);
        const _Float16 tyl = (_Float16)(ty - (float)tyh);
        const _Float16 tzl = (_Float16)(tz - (float)tzh);
        if (half == 0)
            a0 = (half8){-txh, -tyh, -tzh, -txl, -tyl, -tzl, -txh, -tyh};
        else
            a0 = (half8){-tzh, (_Float16)1.f, (_Float16)1.f, 0, 0, 0, 0, 0};
    }
    {
        const int t = min(strip1 * 32 + col, N_TAR - 1);
        const float tx = tar[t * 3 + 0];
        const float ty = tar[t * 3 + 1];
        const float tz = tar[t * 3 + 2];
        const _Float16 txh = (_Float16)tx, tyh = (_Float16)ty, tzh = (_Float16)tz;
        const _Float16 txl = (_Float16)(tx - (float)txh);
        const _Float16 tyl = (_Float16)(ty - (float)tyh);
        const _Float16 tzl = (_Float16)(tz - (float)tzh);
        if (half == 0)
            a1 = (half8){-txh, -tyh, -tzh, -txl, -tyl, -tzl, -txh, -tyh};
        else
            a1 = (half8){-tzh, (_Float16)1.f, (_Float16)1.f, 0, 0, 0, 0, 0};
    }

    __syncthreads();

    // ---- scan tiles in pairs: 2 ds_read_b128 + 4 mfma + 32 v_min3 / 4096 pairs ----
    floatx16 m0, m1;
#pragma unroll
    for (int i = 0; i < 16; ++i) { m0[i] = FLT_MAX; m1[i] = FLT_MAX; }
    const floatx16 zero = {};  // all-zero accumulator init
    const int foff = col * 16 + half * 8;
    for (int tp = 0; tp < TILES; tp += 2) {
        const half8 b0 = *(const half8*)&lds[tp * 512 + foff];
        const half8 b1 = *(const half8*)&lds[(tp + 1) * 512 + foff];
        const floatx16 d0 = __builtin_amdgcn_mfma_f32_32x32x16_f16(a0, b0, zero, 0, 0, 0);
        const floatx16 d1 = __builtin_amdgcn_mfma_f32_32x32x16_f16(a0, b1, zero, 0, 0, 0);
#pragma unroll
        for (int i = 0; i < 16; ++i)
            m0[i] = fminf(fminf(d0[i], d1[i]), m0[i]);  // -> v_min3_f32
        const floatx16 d2 = __builtin_amdgcn_mfma_f32_32x32x16_f16(a1, b0, zero, 0, 0, 0);
        const floatx16 d3 = __builtin_amdgcn_mfma_f32_32x32x16_f16(a1, b1, zero, 0, 0, 0);
#pragma unroll
        for (int i = 0; i < 16; ++i)
            m1[i] = fminf(fminf(d2[i], d3[i]), m1[i]);  // -> v_min3_f32
    }

    // ---- min over the 32 columns (per 32-lane half), then store ----
#pragma unroll
    for (int i = 0; i < 16; ++i) {
        m0[i] = fminf(m0[i], __shfl_xor(m0[i], 1));
        m1[i] = fminf(m1[i], __shfl_xor(m1[i], 1));
        m0[i] = fminf(m0[i], __shfl_xor(m0[i], 2));
        m1[i] = fminf(m1[i], __shfl_xor(m1[i], 2));
        m0[i] = fminf(m0[i], __shfl_xor(m0[i], 4));
        m1[i] = fminf(m1[i], __shfl_xor(m1[i], 4));
        m0[i] = fminf(m0[i], __shfl_xor(m0[i], 8));
        m1[i] = fminf(m1[i], __shfl_xor(m1[i], 8));
        m0[i] = fminf(m0[i], __shfl_xor(m0[i], 16));
        m1[i] = fminf(m1[i], __shfl_xor(m1[i], 16));
    }
    if (col == 0) {
#pragma unroll
        for (int i = 0; i < 16; ++i) {
            const int row = (i & 3) + 8 * (i >> 2) + 4 * half;
            const int t0 = min(strip0 * 32 + row, N_TAR - 1);
            const int t1 = min(strip1 * 32 + row, N_TAR - 1);
            part[blockIdx.y * N_TAR + t0] = m0[i];
            part[blockIdx.y * N_TAR + t1] = m1[i];
        }
    }
}

// combine the SPLITS mins per target, add 0.5||t||^2, reduce into out[0]
__global__ __launch_bounds__(256) void nn_finalize(
    const float* __restrict__ tar, const float* __restrict__ part,
    float* __restrict__ out)
{
    const int t = blockIdx.x * 256 + threadIdx.x;
    float contrib = 0.f;
    if (t < N_TAR) {
        float m = FLT_MAX;
#pragma unroll
        for (int c = 0; c < SPLITS; ++c) m = fminf(m, part[c * N_TAR + t]);
        const float tx = tar[t * 3 + 0];
        const float ty = tar[t * 3 + 1];
        const float tz = tar[t * 3 + 2];
        contrib = 0.5f * (tx * tx + ty * ty + tz * tz) + m;
    }
    for (int off = 32; off > 0; off >>= 1)
        contrib += __shfl_down(contrib, off);
    __shared__ float red[4];
    if ((threadIdx.x & 63) == 0) red[threadIdx.x >> 6] = contrib;
    __syncthreads();
    if (threadIdx.x == 0) {
        float s = 0.f;
#pragma unroll
        for (int w = 0; w < 4; ++w) s += red[w];
        atomicAdd(out, s);
    }
}

extern "C" void kernel_launch(void* const* d_in, const int* in_sizes, int n_in,
                              void* d_out, int out_size, void* d_ws, size_t ws_size,
                              hipStream_t stream) {
    const float* src = (const float*)d_in[0];  // [20000,3] fp32
    const float* tar = (const float*)d_in[1];  // [20000,3] fp32
    float* out = (float*)d_out;                // scalar fp32
    float* part = (float*)d_ws;                // SPLITS * N_TAR floats = 1.28 MB

    dim3 grid1(TGRP, SPLITS);
    nn_mfma<<<grid1, TPB, 0, stream>>>(src, tar, part, out);
    nn_finalize<<<FBLOCKS, 256, 0, stream>>>(tar, part, out);
}